// Round 1
// baseline (605.908 us; speedup 1.0000x reference)
//
#include <hip/hip_runtime.h>
#include <hip/hip_bf16.h>

#define B_ 4
#define S_ 2048
#define D_ 1024
#define H_ 16
#define HD_ 64
#define M_ (B_*S_)

typedef __bf16 bf16;
typedef __bf16 bf16v8 __attribute__((ext_vector_type(8)));
typedef float f32x4 __attribute__((ext_vector_type(4)));

// ---------------- cast fp32 -> bf16 (vectorized, 8/thread) ----------------
__global__ void cast_bf16_kernel(const float* __restrict__ in, bf16* __restrict__ out, int n) {
    int i = (blockIdx.x * blockDim.x + threadIdx.x) * 8;
    if (i >= n) return;
    const float4* p = reinterpret_cast<const float4*>(in + i);
    float4 a = p[0], b = p[1];
    bf16v8 o;
    o[0] = (bf16)a.x; o[1] = (bf16)a.y; o[2] = (bf16)a.z; o[3] = (bf16)a.w;
    o[4] = (bf16)b.x; o[5] = (bf16)b.y; o[6] = (bf16)b.z; o[7] = (bf16)b.w;
    *reinterpret_cast<bf16v8*>(out + i) = o;
}

// ------------- transpose + cast: W[K][N] fp32 -> Wt[N][K] bf16 -------------
__global__ void transpose_cast_kernel(const float* __restrict__ W, bf16* __restrict__ Wt,
                                      int K, int N) {
    __shared__ float tile[32][33];
    int kb = blockIdx.y * 32, nb = blockIdx.x * 32;
    int t = threadIdx.x;          // 256 threads
    int c = t & 31, r0 = t >> 5;  // 8 rows per pass
    for (int i = 0; i < 4; ++i) {
        int r = r0 + i * 8;
        tile[r][c] = W[(size_t)(kb + r) * N + nb + c];
    }
    __syncthreads();
    for (int i = 0; i < 4; ++i) {
        int r = r0 + i * 8;
        Wt[(size_t)(nb + r) * K + kb + c] = (bf16)tile[c][r];
    }
}

// ---------------- GEMM: C[m][n] = sum_k A[m][k]*Bt[n][k] + bias[n] ----------------
// A [M,K] bf16 row-major, Bt [N,K] bf16 row-major. 64x64 tile, 4 waves, BK=32.
template<bool OUT_F32>
__global__ __launch_bounds__(256) void gemm_bt_kernel(const bf16* __restrict__ A,
                                                      const bf16* __restrict__ Bt,
                                                      const float* __restrict__ bias,
                                                      void* __restrict__ Cout,
                                                      int M, int N, int K) {
    __shared__ bf16 Asm[64][32];
    __shared__ bf16 Bsm[64][32];
    int mb = blockIdx.x * 64;
    int nb = blockIdx.y * 64;
    int t = threadIdx.x;
    int w = t >> 6, l = t & 63;
    int wr = w >> 1, wc = w & 1;
    int lg = l >> 4, lr = l & 15;
    f32x4 acc[2][2] = {};
    int arow = t >> 2, acol = (t & 3) * 8;  // 64 rows x 32 cols staging, 8 elems/thread
    for (int k0 = 0; k0 < K; k0 += 32) {
        __syncthreads();
        *reinterpret_cast<bf16v8*>(&Asm[arow][acol]) =
            *reinterpret_cast<const bf16v8*>(&A[(size_t)(mb + arow) * K + k0 + acol]);
        *reinterpret_cast<bf16v8*>(&Bsm[arow][acol]) =
            *reinterpret_cast<const bf16v8*>(&Bt[(size_t)(nb + arow) * K + k0 + acol]);
        __syncthreads();
        bf16v8 af[2], bfr[2];
        af[0]  = *reinterpret_cast<const bf16v8*>(&Asm[wr * 32 + lr][lg * 8]);
        af[1]  = *reinterpret_cast<const bf16v8*>(&Asm[wr * 32 + 16 + lr][lg * 8]);
        bfr[0] = *reinterpret_cast<const bf16v8*>(&Bsm[wc * 32 + lr][lg * 8]);
        bfr[1] = *reinterpret_cast<const bf16v8*>(&Bsm[wc * 32 + 16 + lr][lg * 8]);
        for (int i = 0; i < 2; ++i)
            for (int j = 0; j < 2; ++j)
                acc[i][j] = __builtin_amdgcn_mfma_f32_16x16x32_bf16(af[i], bfr[j], acc[i][j], 0, 0, 0);
    }
    for (int i = 0; i < 2; ++i)
        for (int j = 0; j < 2; ++j) {
            int col = nb + wc * 32 + j * 16 + lr;
            float bv = bias ? bias[col] : 0.f;
            for (int r = 0; r < 4; ++r) {
                int row = mb + wr * 32 + i * 16 + lg * 4 + r;
                float v = acc[i][j][r] + bv;
                if (OUT_F32) ((float*)Cout)[(size_t)row * N + col] = v;
                else         ((bf16*)Cout)[(size_t)row * N + col] = (bf16)v;
            }
        }
}

// ---------------- Flash attention (causal), 64 q-rows/block, 4 waves ----------------
__global__ __launch_bounds__(256) void attn_kernel(const bf16* __restrict__ Q,
                                                   const bf16* __restrict__ Kb,
                                                   const bf16* __restrict__ Vb,
                                                   bf16* __restrict__ O) {
    __shared__ bf16 Ksm[32][64];   // [kv][hd]
    __shared__ bf16 Vts[64][32];   // [hd][kv]
    __shared__ bf16 Ps[4][16][32]; // per-wave P [q][kv]
    int qb = blockIdx.x * 64;
    int bh = blockIdx.y;            // b*H + h
    int b = bh >> 4, h = bh & 15;
    int t = threadIdx.x, w = t >> 6, l = t & 63;
    int lg = l >> 4, lr = l & 15;

    // Q fragments live in registers for the whole kernel
    int qrow = qb + w * 16 + lr;
    const bf16* qptr = Q + ((size_t)(b * S_ + qrow)) * D_ + h * HD_;
    bf16v8 aq[2];
    aq[0] = *reinterpret_cast<const bf16v8*>(qptr + lg * 8);
    aq[1] = *reinterpret_cast<const bf16v8*>(qptr + 32 + lg * 8);

    f32x4 o[4] = {};
    float mrow[4], lsum[4];
    for (int r = 0; r < 4; ++r) { mrow[r] = -__builtin_inff(); lsum[r] = 0.f; }

    int kvend = qb + 64;                 // causal block bound
    int srow = t >> 3, scol = (t & 7) * 8;  // staging: 32 rows x 64 cols, 8/thread
    for (int kv0 = 0; kv0 < kvend; kv0 += 32) {
        __syncthreads();  // previous PV done before restage
        const bf16* kp = &Kb[((size_t)(b * S_ + kv0 + srow)) * D_ + h * HD_ + scol];
        const bf16* vp = &Vb[((size_t)(b * S_ + kv0 + srow)) * D_ + h * HD_ + scol];
        *reinterpret_cast<bf16v8*>(&Ksm[srow][scol]) = *reinterpret_cast<const bf16v8*>(kp);
        bf16v8 vv = *reinterpret_cast<const bf16v8*>(vp);
        for (int j = 0; j < 8; ++j) Vts[scol + j][srow] = vv[j];
        __syncthreads();

        // S = Q K^T  (two 16x16 kv tiles, K-dim = HD = 64 via 2 chained MFMAs)
        f32x4 s[2];
        for (int j = 0; j < 2; ++j) {
            bf16v8 bk0 = *reinterpret_cast<const bf16v8*>(&Ksm[j * 16 + lr][lg * 8]);
            bf16v8 bk1 = *reinterpret_cast<const bf16v8*>(&Ksm[j * 16 + lr][32 + lg * 8]);
            f32x4 z = {};
            z    = __builtin_amdgcn_mfma_f32_16x16x32_bf16(aq[0], bk0, z, 0, 0, 0);
            s[j] = __builtin_amdgcn_mfma_f32_16x16x32_bf16(aq[1], bk1, z, 0, 0, 0);
        }

        // mask + online softmax (rows live in 16-lane groups)
        for (int r = 0; r < 4; ++r) {
            int q = qb + w * 16 + lg * 4 + r;
            float sv[2];
            float m_t = -__builtin_inff();
            for (int j = 0; j < 2; ++j) {
                int kv = kv0 + j * 16 + lr;
                float v = s[j][r] * 0.125f;
                if (kv > q) v = -__builtin_inff();
                sv[j] = v;
                m_t = fmaxf(m_t, v);
            }
            for (int d = 1; d < 16; d <<= 1) m_t = fmaxf(m_t, __shfl_xor(m_t, d, 64));
            float m_new = fmaxf(mrow[r], m_t);
            float sf = __expf(mrow[r] - m_new);   // exp(-inf)=0 handles first iter
            float p0 = __expf(sv[0] - m_new);
            float p1 = __expf(sv[1] - m_new);
            float psum = p0 + p1;
            for (int d = 1; d < 16; d <<= 1) psum += __shfl_xor(psum, d, 64);
            lsum[r] = lsum[r] * sf + psum;
            mrow[r] = m_new;
            for (int n = 0; n < 4; ++n) o[n][r] *= sf;
            Ps[w][lg * 4 + r][lr]      = (bf16)p0;
            Ps[w][lg * 4 + r][16 + lr] = (bf16)p1;
        }
        __syncthreads();  // P visible (also orders Vts reads)

        // O += P V   (A-frag from Ps, B-frag from Vts)
        bf16v8 pa = *reinterpret_cast<const bf16v8*>(&Ps[w][lr][lg * 8]);
        for (int n = 0; n < 4; ++n) {
            bf16v8 bv = *reinterpret_cast<const bf16v8*>(&Vts[n * 16 + lr][lg * 8]);
            o[n] = __builtin_amdgcn_mfma_f32_16x16x32_bf16(pa, bv, o[n], 0, 0, 0);
        }
    }

    for (int n = 0; n < 4; ++n)
        for (int r = 0; r < 4; ++r) {
            int q = qb + w * 16 + lg * 4 + r;
            float v = o[n][r] / lsum[r];
            O[((size_t)(b * S_ + q)) * D_ + h * HD_ + n * 16 + lr] = (bf16)v;
        }
}

extern "C" void kernel_launch(void* const* d_in, const int* in_sizes, int n_in,
                              void* d_out, int out_size, void* d_ws, size_t ws_size,
                              hipStream_t stream) {
    const float* data    = (const float*)d_in[0];
    const float* context = (const float*)d_in[1];
    const float* Wq = (const float*)d_in[2];
    const float* bq = (const float*)d_in[3];
    const float* Wk = (const float*)d_in[4];
    const float* bk = (const float*)d_in[5];
    const float* Wv = (const float*)d_in[6];
    const float* bv = (const float*)d_in[7];
    const float* Wo = (const float*)d_in[8];
    const float* bo = (const float*)d_in[9];
    float* out = (float*)d_out;

    char* ws = (char*)d_ws;
    size_t off = 0;
    auto alloc = [&](size_t bytes) { void* p = ws + off; off += (bytes + 255) & ~255ull; return p; };
    bf16* dataB = (bf16*)alloc((size_t)M_ * D_ * 2);
    bf16* ctxB  = (bf16*)alloc((size_t)M_ * D_ * 2);
    bf16* WqT   = (bf16*)alloc((size_t)D_ * D_ * 2);
    bf16* WkT   = (bf16*)alloc((size_t)D_ * D_ * 2);
    bf16* WvT   = (bf16*)alloc((size_t)D_ * D_ * 2);
    bf16* WoT   = (bf16*)alloc((size_t)D_ * D_ * 2);
    bf16* Qb    = (bf16*)alloc((size_t)M_ * D_ * 2);
    bf16* Kb    = (bf16*)alloc((size_t)M_ * D_ * 2);
    bf16* Vb    = (bf16*)alloc((size_t)M_ * D_ * 2);
    bf16* Ob    = dataB;  // dataB dead after Q projection; reuse for attention output

    int nTok = M_ * D_;  // 8388608
    cast_bf16_kernel<<<nTok / 2048, 256, 0, stream>>>(data, dataB, nTok);
    cast_bf16_kernel<<<nTok / 2048, 256, 0, stream>>>(context, ctxB, nTok);

    dim3 tg(D_ / 32, D_ / 32);
    transpose_cast_kernel<<<tg, 256, 0, stream>>>(Wq, WqT, D_, D_);
    transpose_cast_kernel<<<tg, 256, 0, stream>>>(Wk, WkT, D_, D_);
    transpose_cast_kernel<<<tg, 256, 0, stream>>>(Wv, WvT, D_, D_);
    transpose_cast_kernel<<<tg, 256, 0, stream>>>(Wo, WoT, D_, D_);

    dim3 gg(M_ / 64, D_ / 64);
    gemm_bt_kernel<false><<<gg, 256, 0, stream>>>(dataB, WqT, bq, Qb, M_, D_, D_);
    gemm_bt_kernel<false><<<gg, 256, 0, stream>>>(ctxB,  WkT, bk, Kb, M_, D_, D_);
    gemm_bt_kernel<false><<<gg, 256, 0, stream>>>(ctxB,  WvT, bv, Vb, M_, D_, D_);

    dim3 ag(S_ / 64, B_ * H_);
    attn_kernel<<<ag, 256, 0, stream>>>(Qb, Kb, Vb, Ob);

    gemm_bt_kernel<true><<<gg, 256, 0, stream>>>(Ob, WoT, bo, out, M_, D_, D_);
}

// Round 2
// 328.178 us; speedup vs baseline: 1.8463x; 1.8463x over previous
//
#include <hip/hip_runtime.h>
#include <hip/hip_bf16.h>

#define B_ 4
#define S_ 2048
#define D_ 1024
#define H_ 16
#define HD_ 64
#define M_ (B_*S_)

typedef __bf16 bf16;
typedef __bf16 bf16v4 __attribute__((ext_vector_type(4)));
typedef __bf16 bf16v8 __attribute__((ext_vector_type(8)));
typedef float f32x4 __attribute__((ext_vector_type(4)));

// ---------------- cast fp32 -> bf16 (vectorized, 8/thread) ----------------
__global__ void cast_bf16_kernel(const float* __restrict__ in, bf16* __restrict__ out, int n) {
    int i = (blockIdx.x * blockDim.x + threadIdx.x) * 8;
    if (i >= n) return;
    const float4* p = reinterpret_cast<const float4*>(in + i);
    float4 a = p[0], b = p[1];
    bf16v8 o;
    o[0] = (bf16)a.x; o[1] = (bf16)a.y; o[2] = (bf16)a.z; o[3] = (bf16)a.w;
    o[4] = (bf16)b.x; o[5] = (bf16)b.y; o[6] = (bf16)b.z; o[7] = (bf16)b.w;
    *reinterpret_cast<bf16v8*>(out + i) = o;
}

// ------------- transpose + cast: W[K][N] fp32 -> Wt[N][K] bf16 -------------
__global__ void transpose_cast_kernel(const float* __restrict__ W, bf16* __restrict__ Wt,
                                      int K, int N) {
    __shared__ float tile[32][33];
    int kb = blockIdx.y * 32, nb = blockIdx.x * 32;
    int t = threadIdx.x;
    int c = t & 31, r0 = t >> 5;
    for (int i = 0; i < 4; ++i) {
        int r = r0 + i * 8;
        tile[r][c] = W[(size_t)(kb + r) * N + nb + c];
    }
    __syncthreads();
    for (int i = 0; i < 4; ++i) {
        int r = r0 + i * 8;
        Wt[(size_t)(nb + r) * K + kb + c] = (bf16)tile[c][r];
    }
}

// ------------- per-head transpose: Vb [B,S,D] -> Vt [B*H][HD][S] -------------
__global__ void transpose_v_kernel(const bf16* __restrict__ Vb, bf16* __restrict__ Vt) {
    __shared__ bf16 tile[32][33];
    int sb = blockIdx.x * 32;
    int z = blockIdx.y;            // bh*2 + dtile
    int dt = z & 1, bh = z >> 1;
    int b = bh >> 4, h = bh & 15;
    int t = threadIdx.x;
    int c = t & 31, r0 = t >> 5;
    for (int i = 0; i < 4; ++i) {
        int r = r0 + i * 8;        // s-local
        tile[r][c] = Vb[(size_t)(b * S_ + sb + r) * D_ + h * HD_ + dt * 32 + c];
    }
    __syncthreads();
    for (int i = 0; i < 4; ++i) {
        int r = r0 + i * 8;        // d-local
        Vt[((size_t)bh * HD_ + dt * 32 + r) * S_ + sb + c] = tile[c][r];
    }
}

// ---------------- GEMM: C[m][n] = sum_k A[m][k]*Bt[n][k] + bias[n] ----------------
template<bool OUT_F32>
__global__ __launch_bounds__(256) void gemm_bt_kernel(const bf16* __restrict__ A,
                                                      const bf16* __restrict__ Bt,
                                                      const float* __restrict__ bias,
                                                      void* __restrict__ Cout,
                                                      int M, int N, int K) {
    __shared__ bf16 Asm[64][32];
    __shared__ bf16 Bsm[64][32];
    int mb = blockIdx.x * 64;
    int nb = blockIdx.y * 64;
    int t = threadIdx.x;
    int w = t >> 6, l = t & 63;
    int wr = w >> 1, wc = w & 1;
    int lg = l >> 4, lr = l & 15;
    f32x4 acc[2][2] = {};
    int arow = t >> 2, acol = (t & 3) * 8;
    for (int k0 = 0; k0 < K; k0 += 32) {
        __syncthreads();
        *reinterpret_cast<bf16v8*>(&Asm[arow][acol]) =
            *reinterpret_cast<const bf16v8*>(&A[(size_t)(mb + arow) * K + k0 + acol]);
        *reinterpret_cast<bf16v8*>(&Bsm[arow][acol]) =
            *reinterpret_cast<const bf16v8*>(&Bt[(size_t)(nb + arow) * K + k0 + acol]);
        __syncthreads();
        bf16v8 af[2], bfr[2];
        af[0]  = *reinterpret_cast<const bf16v8*>(&Asm[wr * 32 + lr][lg * 8]);
        af[1]  = *reinterpret_cast<const bf16v8*>(&Asm[wr * 32 + 16 + lr][lg * 8]);
        bfr[0] = *reinterpret_cast<const bf16v8*>(&Bsm[wc * 32 + lr][lg * 8]);
        bfr[1] = *reinterpret_cast<const bf16v8*>(&Bsm[wc * 32 + 16 + lr][lg * 8]);
        for (int i = 0; i < 2; ++i)
            for (int j = 0; j < 2; ++j)
                acc[i][j] = __builtin_amdgcn_mfma_f32_16x16x32_bf16(af[i], bfr[j], acc[i][j], 0, 0, 0);
    }
    for (int i = 0; i < 2; ++i)
        for (int j = 0; j < 2; ++j) {
            int col = nb + wc * 32 + j * 16 + lr;
            float bv = bias ? bias[col] : 0.f;
            for (int r = 0; r < 4; ++r) {
                int row = mb + wr * 32 + i * 16 + lg * 4 + r;
                float v = acc[i][j][r] + bv;
                if (OUT_F32) ((float*)Cout)[(size_t)row * N + col] = v;
                else         ((bf16*)Cout)[(size_t)row * N + col] = (bf16)v;
            }
        }
}

// ---------------- Flash attention (causal), swapped-QK^T, KVBLK=64 ----------------
// 4 waves x 16 q-rows each; K and V^T staged in LDS with 16B-chunk XOR swizzle.
__global__ __launch_bounds__(256) void attn_kernel(const bf16* __restrict__ Q,
                                                   const bf16* __restrict__ Kb,
                                                   const bf16* __restrict__ Vt,
                                                   bf16* __restrict__ O) {
    __shared__ bf16 Ksm[64 * 64];   // [kv][d], chunk-swizzled
    __shared__ bf16 Vsm[64 * 64];   // [d][kv], chunk-swizzled
    __shared__ bf16 Ps[4][16][80];  // per-wave P [q][kv], pad to 80 (160B rows)

    int qb = ((int)gridDim.x - 1 - (int)blockIdx.x) * 64;   // heavy blocks first
    int bh = blockIdx.y;
    int b = bh >> 4, h = bh & 15;
    int t = threadIdx.x, w = t >> 6, l = t & 63;
    int lg = l >> 4, lr = l & 15;

    // Q fragment (B-operand): lane holds Q[q = qb+w*16+lr][d-chunk lg*8]
    int qrow = qb + w * 16 + lr;
    const bf16* qptr = Q + ((size_t)(b * S_ + qrow)) * D_ + h * HD_;
    bf16v8 aq0 = *(const bf16v8*)(qptr + lg * 8);
    bf16v8 aq1 = *(const bf16v8*)(qptr + 32 + lg * 8);

    f32x4 o[4] = {};
    float mrow = -__builtin_inff(), lsum = 0.f;

    int srow = t >> 3;   // 0..31
    int schk = t & 7;    // 16B chunk 0..7
    const bf16* kbase = Kb + (size_t)(b * S_) * D_ + h * HD_;
    const bf16* vbase = Vt + (size_t)bh * HD_ * S_;
    int q = qb + w * 16 + lr;

    for (int kv0 = 0; kv0 < qb + 64; kv0 += 64) {
        // global -> regs (issue before barrier)
        bf16v8 kr0 = *(const bf16v8*)(kbase + (size_t)(kv0 + srow) * D_ + schk * 8);
        bf16v8 kr1 = *(const bf16v8*)(kbase + (size_t)(kv0 + srow + 32) * D_ + schk * 8);
        bf16v8 vr0 = *(const bf16v8*)(vbase + (size_t)srow * S_ + kv0 + schk * 8);
        bf16v8 vr1 = *(const bf16v8*)(vbase + (size_t)(srow + 32) * S_ + kv0 + schk * 8);
        __syncthreads();   // all waves done reading previous tile
        *(bf16v8*)&Ksm[srow * 64 + ((schk ^ (srow & 7)) * 8)]             = kr0;
        *(bf16v8*)&Ksm[(srow + 32) * 64 + ((schk ^ ((srow + 32) & 7)) * 8)] = kr1;
        *(bf16v8*)&Vsm[srow * 64 + ((schk ^ (srow & 7)) * 8)]             = vr0;
        *(bf16v8*)&Vsm[(srow + 32) * 64 + ((schk ^ ((srow + 32) & 7)) * 8)] = vr1;
        __syncthreads();   // tile visible

        // S^T[kv][q] = mfma(K_frag, Q_frag): col=q=lr, row=kv=j*16+lg*4+r
        f32x4 st[4];
        #pragma unroll
        for (int j = 0; j < 4; ++j) {
            int row = j * 16 + lr;
            bf16v8 kf0 = *(const bf16v8*)&Ksm[row * 64 + ((lg ^ (row & 7)) * 8)];
            bf16v8 kf1 = *(const bf16v8*)&Ksm[row * 64 + (((4 + lg) ^ (row & 7)) * 8)];
            f32x4 z = {};
            z     = __builtin_amdgcn_mfma_f32_16x16x32_bf16(kf0, aq0, z, 0, 0, 0);
            st[j] = __builtin_amdgcn_mfma_f32_16x16x32_bf16(kf1, aq1, z, 0, 0, 0);
        }

        // mask (diagonal step only) + scale, in-register row max
        float sv[4][4];
        float mt = -__builtin_inff();
        bool diag = (kv0 == qb);
        #pragma unroll
        for (int j = 0; j < 4; ++j)
            #pragma unroll
            for (int r = 0; r < 4; ++r) {
                float v = st[j][r] * 0.125f;
                if (diag) {
                    int kv = kv0 + j * 16 + lg * 4 + r;
                    if (kv > q) v = -__builtin_inff();
                }
                sv[j][r] = v;
                mt = fmaxf(mt, v);
            }
        mt = fmaxf(mt, __shfl_xor(mt, 16, 64));
        mt = fmaxf(mt, __shfl_xor(mt, 32, 64));
        float mnew = fmaxf(mrow, mt);
        float sf = __expf(mrow - mnew);
        mrow = mnew;

        float psum = 0.f;
        #pragma unroll
        for (int j = 0; j < 4; ++j) {
            bf16v4 pv;
            #pragma unroll
            for (int r = 0; r < 4; ++r) {
                float p = __expf(sv[j][r] - mnew);
                psum += p;
                pv[r] = (bf16)p;
            }
            *(bf16v4*)&Ps[w][lr][j * 16 + lg * 4] = pv;   // 8B write, 4 consecutive kv
        }
        psum += __shfl_xor(psum, 16, 64);
        psum += __shfl_xor(psum, 32, 64);
        lsum = lsum * sf + psum;

        // rescale o (o rows are q = lg*4+r; sf lives at lane lr=q)
        #pragma unroll
        for (int r = 0; r < 4; ++r) {
            float sfo = __shfl(sf, lg * 4 + r, 64);
            #pragma unroll
            for (int n = 0; n < 4; ++n) o[n][r] *= sfo;
        }

        // O += P V : A-frag from Ps[q][kv], B-frag from Vsm[d][kv]
        #pragma unroll
        for (int c = 0; c < 2; ++c) {
            bf16v8 pa = *(const bf16v8*)&Ps[w][lr][c * 32 + lg * 8];
            #pragma unroll
            for (int n = 0; n < 4; ++n) {
                int row = n * 16 + lr;
                bf16v8 bv = *(const bf16v8*)&Vsm[row * 64 + (((c * 4 + lg) ^ (row & 7)) * 8)];
                o[n] = __builtin_amdgcn_mfma_f32_16x16x32_bf16(pa, bv, o[n], 0, 0, 0);
            }
        }
    }

    // epilogue: lane holds O[q=lg*4+r][d=n*16+lr]; lsum lives at lane lr=q
    #pragma unroll
    for (int r = 0; r < 4; ++r) {
        float li = 1.f / __shfl(lsum, lg * 4 + r, 64);
        int qq = qb + w * 16 + lg * 4 + r;
        #pragma unroll
        for (int n = 0; n < 4; ++n)
            O[((size_t)(b * S_ + qq)) * D_ + h * HD_ + n * 16 + lr] = (bf16)(o[n][r] * li);
    }
}

extern "C" void kernel_launch(void* const* d_in, const int* in_sizes, int n_in,
                              void* d_out, int out_size, void* d_ws, size_t ws_size,
                              hipStream_t stream) {
    const float* data    = (const float*)d_in[0];
    const float* context = (const float*)d_in[1];
    const float* Wq = (const float*)d_in[2];
    const float* bq = (const float*)d_in[3];
    const float* Wk = (const float*)d_in[4];
    const float* bk = (const float*)d_in[5];
    const float* Wv = (const float*)d_in[6];
    const float* bv = (const float*)d_in[7];
    const float* Wo = (const float*)d_in[8];
    const float* bo = (const float*)d_in[9];
    float* out = (float*)d_out;

    char* ws = (char*)d_ws;
    size_t off = 0;
    auto alloc = [&](size_t bytes) { void* p = ws + off; off += (bytes + 255) & ~255ull; return p; };
    bf16* dataB = (bf16*)alloc((size_t)M_ * D_ * 2);
    bf16* ctxB  = (bf16*)alloc((size_t)M_ * D_ * 2);
    bf16* WqT   = (bf16*)alloc((size_t)D_ * D_ * 2);
    bf16* WkT   = (bf16*)alloc((size_t)D_ * D_ * 2);
    bf16* WvT   = (bf16*)alloc((size_t)D_ * D_ * 2);
    bf16* WoT   = (bf16*)alloc((size_t)D_ * D_ * 2);
    bf16* Qb    = (bf16*)alloc((size_t)M_ * D_ * 2);
    bf16* Kb    = (bf16*)alloc((size_t)M_ * D_ * 2);
    bf16* Vb    = (bf16*)alloc((size_t)M_ * D_ * 2);
    bf16* Vt    = dataB;  // dataB dead after Q projection
    bf16* Ob    = ctxB;   // ctxB dead after K/V projections

    int nTok = M_ * D_;
    cast_bf16_kernel<<<nTok / 2048, 256, 0, stream>>>(data, dataB, nTok);
    cast_bf16_kernel<<<nTok / 2048, 256, 0, stream>>>(context, ctxB, nTok);

    dim3 tg(D_ / 32, D_ / 32);
    transpose_cast_kernel<<<tg, 256, 0, stream>>>(Wq, WqT, D_, D_);
    transpose_cast_kernel<<<tg, 256, 0, stream>>>(Wk, WkT, D_, D_);
    transpose_cast_kernel<<<tg, 256, 0, stream>>>(Wv, WvT, D_, D_);
    transpose_cast_kernel<<<tg, 256, 0, stream>>>(Wo, WoT, D_, D_);

    dim3 gg(M_ / 64, D_ / 64);
    gemm_bt_kernel<false><<<gg, 256, 0, stream>>>(dataB, WqT, bq, Qb, M_, D_, D_);
    gemm_bt_kernel<false><<<gg, 256, 0, stream>>>(ctxB,  WkT, bk, Kb, M_, D_, D_);
    gemm_bt_kernel<false><<<gg, 256, 0, stream>>>(ctxB,  WvT, bv, Vb, M_, D_, D_);

    dim3 vt(S_ / 32, 2 * B_ * H_);
    transpose_v_kernel<<<vt, 256, 0, stream>>>(Vb, Vt);

    dim3 ag(S_ / 64, B_ * H_);
    attn_kernel<<<ag, 256, 0, stream>>>(Qb, Kb, Vt, Ob);

    gemm_bt_kernel<true><<<gg, 256, 0, stream>>>(Ob, WoT, bo, out, M_, D_, D_);
}